// Round 6
// baseline (532.704 us; speedup 1.0000x reference)
//
#include <hip/hip_runtime.h>
#include <hip/hip_bf16.h>
#include <stdint.h>

#define B_ 4
#define H_ 16
#define S_ 2048
#define D_ 64
#define NKT (S_ / 64)
#define QM 128

typedef __attribute__((ext_vector_type(8))) short bf16x8;
typedef __attribute__((ext_vector_type(4))) float f32x4;
typedef unsigned long long u64;
typedef unsigned int u32;

__device__ inline short f2bf(float f) {
  union { float f; u32 u; } x; x.f = f;
  u32 r = x.u + 0x7FFFu + ((x.u >> 16) & 1u);
  return (short)(r >> 16);
}
__device__ inline short4 f2bf4(float4 v) {
  short4 s; s.x = f2bf(v.x); s.y = f2bf(v.y); s.z = f2bf(v.z); s.w = f2bf(v.w);
  return s;
}

// XOR-swizzled byte offset in a row x 128-byte tile image
__device__ inline int SW(int row, int byteoff) {
  return row * 128 + (byteoff ^ ((row & 7) << 4));
}

__device__ inline void gll16(const void* g, void* l) {
  __builtin_amdgcn_global_load_lds(
      (const __attribute__((address_space(1))) u32*)g,
      (__attribute__((address_space(3))) u32*)(uintptr_t)l, 16, 0, 0);
}

// ---------------- fused prepass ----------------
// blocks [0,8192):        K fp32 -> bf16 swizzled rows
// blocks [8192,10240):    V fp32 -> bf16 transposed 64-key tiles (2048 tiles)
// blocks [10240,26624):   mask int32 -> packed u64 bits
__global__ __launch_bounds__(256)
void prepass(const float* __restrict__ Kg, const float* __restrict__ Vg,
             const int* __restrict__ Mg,
             char* __restrict__ Ksw, char* __restrict__ Vsw, u64* __restrict__ Mp) {
  __shared__ short tile[4096];
  const int bid = blockIdx.x, tid = threadIdx.x;
  if (bid < 8192) {
    int idx = bid * 256 + tid;
    int row = idx >> 4, c4 = idx & 15;
    float4 v = *(const float4*)(Kg + (size_t)idx * 4);
    *(short4*)(Ksw + (size_t)row * 128 + ((c4 * 8) ^ ((row & 7) << 4))) = f2bf4(v);
  } else if (bid < 10240) {
    int vb = bid - 8192;
    char* ct = (char*)tile;
    int c4 = tid & 15, g = tid >> 4;
    const float* src = Vg + (size_t)vb * (64 * D_) + (size_t)(g * 4) * D_ + c4 * 4;
    float4 vv[4];
#pragma unroll
    for (int i = 0; i < 4; ++i) vv[i] = *(const float4*)(src + (size_t)i * D_);
    const float* vf = (const float*)vv;
#pragma unroll
    for (int dd = 0; dd < 4; ++dd) {
      short4 s;
      s.x = f2bf(vf[0 * 4 + dd]);
      s.y = f2bf(vf[1 * 4 + dd]);
      s.z = f2bf(vf[2 * 4 + dd]);
      s.w = f2bf(vf[3 * 4 + dd]);
      *(short4*)(ct + SW(c4 * 4 + dd, g * 8)) = s;
    }
    __syncthreads();
    char* dst = Vsw + (size_t)vb * 8192;
#pragma unroll
    for (int j = 0; j < 2; ++j)
      *(float4*)(dst + tid * 16 + j * 4096) = *(const float4*)(ct + tid * 16 + j * 4096);
  } else {
    int pb = bid - 10240;
    int gbase = pb * 1024;
#pragma unroll
    for (int j = 0; j < 4; ++j) {
      int idx = gbase + j * 256 + tid;
      u64 bits = __ballot(Mg[idx] != 0);
      if ((tid & 63) == 0) Mp[idx >> 6] = bits;
    }
  }
}

// ---------------- main kernel ----------------
// LDS: sK 16K dbuf + sV 16K dbuf + sP 8K strip = 40960 B -> 4 blocks/CU exact.
__global__ __launch_bounds__(256, 4)
void attn_kernel(const float* __restrict__ Qg,
                 const char* __restrict__ Ksw,
                 const char* __restrict__ Vsw,
                 const u64* __restrict__ Mp,
                 float* __restrict__ Og) {
  __shared__ short sK[2][4096];
  __shared__ short sV[2][4096];
  __shared__ short sP[4096];   // 4 waves x 16-row strips (reused for gi=0,1)

  const int tid  = threadIdx.x;
  const int w    = tid >> 6;
  const int lane = tid & 63;
  const int quad = lane >> 4;
  const int c    = lane & 15;
  const int bh   = blockIdx.y;
  const int b    = bh >> 4;            // H_ == 16
  const int q0   = blockIdx.x * QM;
  const size_t base = (size_t)bh * (S_ * D_);
  const char* Kt = Ksw + (size_t)bh * (S_ * 128);
  const char* Vt = Vsw + (size_t)bh * (S_ * 128);
  char* cK0 = (char*)sK;               // 16 KB contiguous, doubles as Q stage
  char* strip = (char*)sP + w * 2048;  // wave-private 16 rows x 128 B

  // ---- stage Q (pre-scaled into log2 domain) into the sK area ----
  const float SC = 0.125f * 1.44269504088896f;   // 1/sqrt(64) * log2(e)
#pragma unroll
  for (int j = 0; j < 8; ++j) {
    int idx = tid + j * 256;
    int row = idx >> 4, c4 = idx & 15;
    float4 v = *(const float4*)(Qg + base + (size_t)(q0 + row) * D_ + c4 * 4);
    v.x *= SC; v.y *= SC; v.z *= SC; v.w *= SC;
    *(short4*)(cK0 + SW(row, c4 * 8)) = f2bf4(v);
  }
  __syncthreads();
  bf16x8 qa[2][2];
#pragma unroll
  for (int gi = 0; gi < 2; ++gi) {
    qa[gi][0] = *(bf16x8*)(cK0 + SW(32 * w + 16 * gi + c, quad * 16));
    qa[gi][1] = *(bf16x8*)(cK0 + SW(32 * w + 16 * gi + c, 64 + quad * 16));
  }
  __syncthreads();   // all Q reads done; sK area may now be overwritten

  // issue tile-0 async staging
#pragma unroll
  for (int j = 0; j < 2; ++j) {
    gll16(Kt + tid * 16 + j * 4096, (char*)sK[0] + tid * 16 + j * 4096);
    gll16(Vt + tid * 16 + j * 4096, (char*)sV[0] + tid * 16 + j * 4096);
  }

  f32x4 acco[2][4];
  float2 l2[2][4];
#pragma unroll
  for (int gi = 0; gi < 2; ++gi)
#pragma unroll
    for (int i = 0; i < 4; ++i) { acco[gi][i] = f32x4{0,0,0,0}; l2[gi][i] = make_float2(0.f, 0.f); }

  const u64* mrow[2];
  mrow[0] = Mp + ((size_t)b * S_ + q0 + 32 * w + quad * 4) * NKT;
  mrow[1] = mrow[0] + 16 * NKT;

  u64 mw[2][4];
#pragma unroll
  for (int gi = 0; gi < 2; ++gi)
#pragma unroll
    for (int r = 0; r < 4; ++r) mw[gi][r] = mrow[gi][(size_t)r * NKT];

#pragma unroll 2
  for (int kt = 0; kt < NKT; ++kt) {
    const char* cK = (const char*)sK[kt & 1];
    const char* cV = (const char*)sV[kt & 1];

    __syncthreads();   // tile kt resident (drains gll); prev reads of other buf done

    if (kt + 1 < NKT) {
      char* kn = (char*)sK[(kt + 1) & 1];
      char* vn = (char*)sV[(kt + 1) & 1];
      const char* kg = Kt + (size_t)(kt + 1) * 8192;
      const char* vg = Vt + (size_t)(kt + 1) * 8192;
#pragma unroll
      for (int j = 0; j < 2; ++j) {
        gll16(kg + tid * 16 + j * 4096, kn + tid * 16 + j * 4096);
        gll16(vg + tid * 16 + j * 4096, vn + tid * 16 + j * 4096);
      }
    }
    const int ktn = (kt + 1 < NKT) ? kt + 1 : kt;
    u64 mwn[2][4];
#pragma unroll
    for (int gi = 0; gi < 2; ++gi)
#pragma unroll
      for (int r = 0; r < 4; ++r) mwn[gi][r] = mrow[gi][(size_t)r * NKT + ktn];

    // ---- scores: S = Q K^T (log2 domain via pre-scaled Q) ----
    f32x4 accs[2][4];
#pragma unroll
    for (int n = 0; n < 4; ++n) {
      bf16x8 kb0 = *(bf16x8*)(cK + SW(16 * n + c, quad * 16));
      bf16x8 kb1 = *(bf16x8*)(cK + SW(16 * n + c, 64 + quad * 16));
#pragma unroll
      for (int gi = 0; gi < 2; ++gi) {
        f32x4 z = {0, 0, 0, 0};
        z = __builtin_amdgcn_mfma_f32_16x16x32_bf16(qa[gi][0], kb0, z, 0, 0, 0);
        z = __builtin_amdgcn_mfma_f32_16x16x32_bf16(qa[gi][1], kb1, z, 0, 0, 0);
        accs[gi][n] = z;
      }
    }

    // ---- softmax numerator + P transform, one gi phase at a time ----
    bf16x8 pa[2][2];
#pragma unroll
    for (int gi = 0; gi < 2; ++gi) {
#pragma unroll
      for (int r = 0; r < 4; ++r) {
        unsigned mlo = (unsigned)(mw[gi][r]) >> c;
        unsigned mhi = (unsigned)(mw[gi][r] >> 32) >> c;
        float e0 = (mlo & 1u)         ? exp2f(accs[gi][0][r]) : 0.0f;
        float e1 = ((mlo >> 16) & 1u) ? exp2f(accs[gi][1][r]) : 0.0f;
        float e2 = (mhi & 1u)         ? exp2f(accs[gi][2][r]) : 0.0f;
        float e3 = ((mhi >> 16) & 1u) ? exp2f(accs[gi][3][r]) : 0.0f;
        float2 s01 = make_float2(e0, e1), s23 = make_float2(e2, e3);
        l2[gi][r].x += s01.x + s23.x;
        l2[gi][r].y += s01.y + s23.y;
        // packed f32->bf16 pairs (v_cvt_pk_bf16_f32)
        union { __hip_bfloat162 h; short s[2]; } p01, p23;
        p01.h = __float22bfloat162_rn(s01);
        p23.h = __float22bfloat162_rn(s23);
        int prow = quad * 4 + r;
        *(short*)(strip + SW(prow, (c) * 2))      = p01.s[0];
        *(short*)(strip + SW(prow, (16 + c) * 2)) = p01.s[1];
        *(short*)(strip + SW(prow, (32 + c) * 2)) = p23.s[0];
        *(short*)(strip + SW(prow, (48 + c) * 2)) = p23.s[1];
      }
      // read back this gi's A-fragment (in-wave LDS ordering; strip reused next gi)
      pa[gi][0] = *(bf16x8*)(strip + SW(c, quad * 16));
      pa[gi][1] = *(bf16x8*)(strip + SW(c, 64 + quad * 16));
    }
#pragma unroll
    for (int gi = 0; gi < 2; ++gi)
#pragma unroll
      for (int r = 0; r < 4; ++r) mw[gi][r] = mwn[gi][r];

    // ---- O += P V ----
#pragma unroll
    for (int dn = 0; dn < 4; ++dn) {
      bf16x8 vb0 = *(bf16x8*)(cV + SW(16 * dn + c, quad * 16));
      bf16x8 vb1 = *(bf16x8*)(cV + SW(16 * dn + c, 64 + quad * 16));
#pragma unroll
      for (int gi = 0; gi < 2; ++gi) {
        acco[gi][dn] = __builtin_amdgcn_mfma_f32_16x16x32_bf16(pa[gi][0], vb0, acco[gi][dn], 0, 0, 0);
        acco[gi][dn] = __builtin_amdgcn_mfma_f32_16x16x32_bf16(pa[gi][1], vb1, acco[gi][dn], 0, 0, 0);
      }
    }
  }

  // ---- epilogue: reduce l across the 16-lane row group, normalize, store ----
#pragma unroll
  for (int gi = 0; gi < 2; ++gi) {
#pragma unroll
    for (int r = 0; r < 4; ++r) {
      float l = l2[gi][r].x + l2[gi][r].y;
      l += __shfl_xor(l, 1);
      l += __shfl_xor(l, 2);
      l += __shfl_xor(l, 4);
      l += __shfl_xor(l, 8);
      float inv = 1.0f / l;
      size_t orow = base + (size_t)(q0 + 32 * w + 16 * gi + quad * 4 + r) * D_;
#pragma unroll
      for (int dn = 0; dn < 4; ++dn)
        Og[orow + 16 * dn + c] = acco[gi][dn][r] * inv;
    }
  }
}

extern "C" void kernel_launch(void* const* d_in, const int* in_sizes, int n_in,
                              void* d_out, int out_size, void* d_ws, size_t ws_size,
                              hipStream_t stream) {
  const float* Kg = (const float*)d_in[0];  // key
  const float* Qg = (const float*)d_in[1];  // query
  const float* Vg = (const float*)d_in[2];  // value
  const int*   Mg = (const int*)d_in[3];    // mask
  float* Og = (float*)d_out;

  char* ws  = (char*)d_ws;
  u64*  Mp  = (u64*)ws;                                  // 2 MiB
  char* Ksw = ws + (size_t)(2u << 20);                   // 16 MiB
  char* Vsw = ws + (size_t)(2u << 20) + (16u << 20);     // 16 MiB

  prepass<<<26624, 256, 0, stream>>>(Kg, Vg, Mg, Ksw, Vsw, Mp);
  attn_kernel<<<dim3(S_ / QM, B_ * H_), 256, 0, stream>>>(Qg, Ksw, Vsw, Mp, Og);
}

// Round 7
// 325.698 us; speedup vs baseline: 1.6356x; 1.6356x over previous
//
#include <hip/hip_runtime.h>
#include <hip/hip_bf16.h>
#include <stdint.h>

#define B_ 4
#define H_ 16
#define S_ 2048
#define D_ 64
#define NKT (S_ / 64)
#define QM 128

typedef __attribute__((ext_vector_type(8))) short bf16x8;
typedef __attribute__((ext_vector_type(4))) float f32x4;
typedef unsigned long long u64;
typedef unsigned int u32;

__device__ inline short f2bf(float f) {
  union { float f; u32 u; } x; x.f = f;
  u32 r = x.u + 0x7FFFu + ((x.u >> 16) & 1u);
  return (short)(r >> 16);
}
__device__ inline short4 f2bf4(float4 v) {
  short4 s; s.x = f2bf(v.x); s.y = f2bf(v.y); s.z = f2bf(v.z); s.w = f2bf(v.w);
  return s;
}

// XOR-swizzled byte offset in a row x 128-byte tile image
__device__ inline int SW(int row, int byteoff) {
  return row * 128 + (byteoff ^ ((row & 7) << 4));
}

__device__ inline void gll16(const void* g, void* l) {
  __builtin_amdgcn_global_load_lds(
      (const __attribute__((address_space(1))) u32*)g,
      (__attribute__((address_space(3))) u32*)(uintptr_t)l, 16, 0, 0);
}

// ---------------- fused prepass ----------------
// blocks [0,8192):        K fp32 -> bf16 swizzled rows
// blocks [8192,10240):    V fp32 -> bf16 transposed 64-key tiles (2048 tiles)
// blocks [10240,26624):   mask int32 -> packed u64 bits
__global__ __launch_bounds__(256)
void prepass(const float* __restrict__ Kg, const float* __restrict__ Vg,
             const int* __restrict__ Mg,
             char* __restrict__ Ksw, char* __restrict__ Vsw, u64* __restrict__ Mp) {
  __shared__ short tile[4096];
  const int bid = blockIdx.x, tid = threadIdx.x;
  if (bid < 8192) {
    int idx = bid * 256 + tid;
    int row = idx >> 4, c4 = idx & 15;
    float4 v = *(const float4*)(Kg + (size_t)idx * 4);
    *(short4*)(Ksw + (size_t)row * 128 + ((c4 * 8) ^ ((row & 7) << 4))) = f2bf4(v);
  } else if (bid < 10240) {
    int vb = bid - 8192;
    char* ct = (char*)tile;
    int c4 = tid & 15, g = tid >> 4;
    const float* src = Vg + (size_t)vb * (64 * D_) + (size_t)(g * 4) * D_ + c4 * 4;
    float4 vv[4];
#pragma unroll
    for (int i = 0; i < 4; ++i) vv[i] = *(const float4*)(src + (size_t)i * D_);
    const float* vf = (const float*)vv;
#pragma unroll
    for (int dd = 0; dd < 4; ++dd) {
      short4 s;
      s.x = f2bf(vf[0 * 4 + dd]);
      s.y = f2bf(vf[1 * 4 + dd]);
      s.z = f2bf(vf[2 * 4 + dd]);
      s.w = f2bf(vf[3 * 4 + dd]);
      *(short4*)(ct + SW(c4 * 4 + dd, g * 8)) = s;
    }
    __syncthreads();
    char* dst = Vsw + (size_t)vb * 8192;
#pragma unroll
    for (int j = 0; j < 2; ++j)
      *(float4*)(dst + tid * 16 + j * 4096) = *(const float4*)(ct + tid * 16 + j * 4096);
  } else {
    int pb = bid - 10240;
    int gbase = pb * 1024;
#pragma unroll
    for (int j = 0; j < 4; ++j) {
      int idx = gbase + j * 256 + tid;
      u64 bits = __ballot(Mg[idx] != 0);
      if ((tid & 63) == 0) Mp[idx >> 6] = bits;
    }
  }
}

// ---------------- main kernel ----------------
// LDS: sK 16K dbuf + sV 16K dbuf = 32768 B -> 4 blocks/CU (with runtime reserve).
// P strips alias the dead K read-buffer after the score phase (barrier-protected).
__global__ __launch_bounds__(256, 3)
void attn_kernel(const float* __restrict__ Qg,
                 const char* __restrict__ Ksw,
                 const char* __restrict__ Vsw,
                 const u64* __restrict__ Mp,
                 float* __restrict__ Og) {
  __shared__ short sK[2][4096];
  __shared__ short sV[2][4096];

  const int tid  = threadIdx.x;
  const int w    = tid >> 6;
  const int lane = tid & 63;
  const int quad = lane >> 4;
  const int c    = lane & 15;
  const int bh   = blockIdx.y;
  const int b    = bh >> 4;            // H_ == 16
  const int q0   = blockIdx.x * QM;
  const size_t base = (size_t)bh * (S_ * D_);
  const char* Kt = Ksw + (size_t)bh * (S_ * 128);
  const char* Vt = Vsw + (size_t)bh * (S_ * 128);
  char* cK0 = (char*)sK;               // 16 KB contiguous, doubles as Q stage

  // ---- stage Q (pre-scaled into log2 domain) into the sK area ----
  const float SC = 0.125f * 1.44269504088896f;   // 1/sqrt(64) * log2(e)
#pragma unroll
  for (int j = 0; j < 8; ++j) {
    int idx = tid + j * 256;
    int row = idx >> 4, c4 = idx & 15;
    float4 v = *(const float4*)(Qg + base + (size_t)(q0 + row) * D_ + c4 * 4);
    v.x *= SC; v.y *= SC; v.z *= SC; v.w *= SC;
    *(short4*)(cK0 + SW(row, c4 * 8)) = f2bf4(v);
  }
  __syncthreads();
  bf16x8 qa[2][2];
#pragma unroll
  for (int gi = 0; gi < 2; ++gi) {
    qa[gi][0] = *(bf16x8*)(cK0 + SW(32 * w + 16 * gi + c, quad * 16));
    qa[gi][1] = *(bf16x8*)(cK0 + SW(32 * w + 16 * gi + c, 64 + quad * 16));
  }
  __syncthreads();   // all Q reads done; sK area may now be overwritten

  // issue tile-0 async staging
#pragma unroll
  for (int j = 0; j < 2; ++j) {
    gll16(Kt + tid * 16 + j * 4096, (char*)sK[0] + tid * 16 + j * 4096);
    gll16(Vt + tid * 16 + j * 4096, (char*)sV[0] + tid * 16 + j * 4096);
  }

  f32x4 acco[2][4];
  float l_part[2][4];
#pragma unroll
  for (int gi = 0; gi < 2; ++gi)
#pragma unroll
    for (int i = 0; i < 4; ++i) { acco[gi][i] = f32x4{0,0,0,0}; l_part[gi][i] = 0.f; }

  const u64* mrow[2];
  mrow[0] = Mp + ((size_t)b * S_ + q0 + 32 * w + quad * 4) * NKT;
  mrow[1] = mrow[0] + 16 * NKT;

  for (int kt = 0; kt < NKT; ++kt) {
    const char* cK = (const char*)sK[kt & 1];
    const char* cV = (const char*)sV[kt & 1];
    char* strip = (char*)sK[kt & 1] + w * 2048;  // aliased after score phase

    __syncthreads();   // barrier A: gll(kt) drained; prev iter strip/V reads done

    // mask words for this tile (L2-hit latency hidden under the score MFMAs)
    u64 mw[2][4];
#pragma unroll
    for (int gi = 0; gi < 2; ++gi)
#pragma unroll
      for (int r = 0; r < 4; ++r) mw[gi][r] = mrow[gi][(size_t)r * NKT + kt];

    // ---- scores: S = Q K^T (log2 domain via pre-scaled Q) ----
    f32x4 accs[2][4];
#pragma unroll
    for (int n = 0; n < 4; ++n) {
      bf16x8 kb0 = *(bf16x8*)(cK + SW(16 * n + c, quad * 16));
      bf16x8 kb1 = *(bf16x8*)(cK + SW(16 * n + c, 64 + quad * 16));
#pragma unroll
      for (int gi = 0; gi < 2; ++gi) {
        f32x4 z = {0, 0, 0, 0};
        z = __builtin_amdgcn_mfma_f32_16x16x32_bf16(qa[gi][0], kb0, z, 0, 0, 0);
        z = __builtin_amdgcn_mfma_f32_16x16x32_bf16(qa[gi][1], kb1, z, 0, 0, 0);
        accs[gi][n] = z;
      }
    }

    __syncthreads();   // barrier B: all waves done reading sK[kt&1]; strips may alias it

    // async prefetch tile kt+1 (issued AFTER barrier B so it isn't drained mid-iter;
    // stays in flight through exp2+PV and is collected at the next barrier A)
    if (kt + 1 < NKT) {
      char* kn = (char*)sK[(kt + 1) & 1];
      char* vn = (char*)sV[(kt + 1) & 1];
      const char* kg = Kt + (size_t)(kt + 1) * 8192;
      const char* vg = Vt + (size_t)(kt + 1) * 8192;
#pragma unroll
      for (int j = 0; j < 2; ++j) {
        gll16(kg + tid * 16 + j * 4096, kn + tid * 16 + j * 4096);
        gll16(vg + tid * 16 + j * 4096, vn + tid * 16 + j * 4096);
      }
    }

    // ---- softmax numerator + C->A transform via aliased wave-private strip ----
    bf16x8 pa[2][2];
#pragma unroll
    for (int gi = 0; gi < 2; ++gi) {
#pragma unroll
      for (int r = 0; r < 4; ++r) {
        unsigned mlo = (unsigned)(mw[gi][r]) >> c;
        unsigned mhi = (unsigned)(mw[gi][r] >> 32) >> c;
        float e0 = (mlo & 1u)         ? exp2f(accs[gi][0][r]) : 0.0f;
        float e1 = ((mlo >> 16) & 1u) ? exp2f(accs[gi][1][r]) : 0.0f;
        float e2 = (mhi & 1u)         ? exp2f(accs[gi][2][r]) : 0.0f;
        float e3 = ((mhi >> 32 - 32 + 16) & 1u) ? exp2f(accs[gi][3][r]) : 0.0f;
        l_part[gi][r] += (e0 + e1) + (e2 + e3);
        union { __hip_bfloat162 h; short s[2]; } p01, p23;
        p01.h = __float22bfloat162_rn(make_float2(e0, e1));
        p23.h = __float22bfloat162_rn(make_float2(e2, e3));
        int prow = quad * 4 + r;
        *(short*)(strip + SW(prow, (c) * 2))      = p01.s[0];
        *(short*)(strip + SW(prow, (16 + c) * 2)) = p01.s[1];
        *(short*)(strip + SW(prow, (32 + c) * 2)) = p23.s[0];
        *(short*)(strip + SW(prow, (48 + c) * 2)) = p23.s[1];
      }
      // read back this gi's A-fragment (wave-local LDS ordering; strip reused next gi)
      pa[gi][0] = *(bf16x8*)(strip + SW(c, quad * 16));
      pa[gi][1] = *(bf16x8*)(strip + SW(c, 64 + quad * 16));
    }

    // ---- O += P V ----
#pragma unroll
    for (int dn = 0; dn < 4; ++dn) {
      bf16x8 vb0 = *(bf16x8*)(cV + SW(16 * dn + c, quad * 16));
      bf16x8 vb1 = *(bf16x8*)(cV + SW(16 * dn + c, 64 + quad * 16));
#pragma unroll
      for (int gi = 0; gi < 2; ++gi) {
        acco[gi][dn] = __builtin_amdgcn_mfma_f32_16x16x32_bf16(pa[gi][0], vb0, acco[gi][dn], 0, 0, 0);
        acco[gi][dn] = __builtin_amdgcn_mfma_f32_16x16x32_bf16(pa[gi][1], vb1, acco[gi][dn], 0, 0, 0);
      }
    }
  }

  // ---- epilogue: reduce l across the 16-lane row group, normalize, store ----
#pragma unroll
  for (int gi = 0; gi < 2; ++gi) {
#pragma unroll
    for (int r = 0; r < 4; ++r) {
      float l = l_part[gi][r];
      l += __shfl_xor(l, 1);
      l += __shfl_xor(l, 2);
      l += __shfl_xor(l, 4);
      l += __shfl_xor(l, 8);
      float inv = 1.0f / l;
      size_t orow = base + (size_t)(q0 + 32 * w + 16 * gi + quad * 4 + r) * D_;
#pragma unroll
      for (int dn = 0; dn < 4; ++dn)
        Og[orow + 16 * dn + c] = acco[gi][dn][r] * inv;
    }
  }
}

extern "C" void kernel_launch(void* const* d_in, const int* in_sizes, int n_in,
                              void* d_out, int out_size, void* d_ws, size_t ws_size,
                              hipStream_t stream) {
  const float* Kg = (const float*)d_in[0];  // key
  const float* Qg = (const float*)d_in[1];  // query
  const float* Vg = (const float*)d_in[2];  // value
  const int*   Mg = (const int*)d_in[3];    // mask
  float* Og = (float*)d_out;

  char* ws  = (char*)d_ws;
  u64*  Mp  = (u64*)ws;                                  // 2 MiB
  char* Ksw = ws + (size_t)(2u << 20);                   // 16 MiB
  char* Vsw = ws + (size_t)(2u << 20) + (16u << 20);     // 16 MiB

  prepass<<<26624, 256, 0, stream>>>(Kg, Vg, Mg, Ksw, Vsw, Mp);
  attn_kernel<<<dim3(S_ / QM, B_ * H_), 256, 0, stream>>>(Qg, Ksw, Vsw, Mp, Og);
}